// Round 7
// baseline (268.952 us; speedup 1.0000x reference)
//
#include <hip/hip_runtime.h>

#define N_ENT   50000
#define CH      128
#define N_EDGES 1600000
#define N_RELM1 10
#define NB      391           // ceil(N_ENT / 128) buckets of 128 heads
#define BCAP    4608          // real-entry bucket capacity (verified max fits)
#define BCAP_P  8192          // padded csr capacity: 4608 + 512 bins * 7 = 8192 (proven bound)
#define PART_BLOCKS 800
#define CHUNK   (N_EDGES / PART_BLOCKS)   // 2000 exactly
#define NRG     (N_ENT / 4)   // 12500 rowgroups of 4 heads (TLP: 32 waves/CU)
#define NKEY    512           // (rgl:5)(g2:2)(r:2) sort bins per bucket
#define EPS_N   1e-12f

#define RFL(x) __builtin_amdgcn_readfirstlane(x)

__device__ __forceinline__ unsigned int f2bf_bits(float f) {
    unsigned int x = __float_as_uint(f);
    return (x + 0x7FFFu + ((x >> 16) & 1u)) >> 16;   // RNE; values are finite
}

// Per block: ONE pass over its 2000 edges, stage entry+bucket in LDS,
// histogram, scan, LDS bin-scatter, coalesced write-out. Fused bf16 cvt.
// entry = tail(16) | rel(4)<<16 | hlow(7)<<20
__global__ __launch_bounds__(256) void gc_part_kernel(const int* __restrict__ head,
                                                      const int* __restrict__ tail,
                                                      const int* __restrict__ etyp,
                                                      int* __restrict__ barr,
                                                      int* __restrict__ pack,
                                                      const float* __restrict__ ent,
                                                      unsigned int* __restrict__ emb) {
    __shared__ int hist[512];                // NB bins padded
    __shared__ int boff_s[512];
    __shared__ int fctr[512];
    __shared__ int psum[256];
    __shared__ int stageE[CHUNK];            // raw entries (8 KB)
    __shared__ unsigned short stageB[CHUNK]; // bucket ids (4 KB)
    __shared__ int stage2[CHUNK];            // binned entries (8 KB)
    int tid = threadIdx.x, blk = blockIdx.x;
    for (int i = tid; i < 512; i += 256) { hist[i] = 0; fctr[i] = 0; }
    __syncthreads();
    int lo = blk * CHUNK;
    for (int i = tid; i < CHUNK; i += 256) {
        int e = lo + i;
        int h = head[e];
        int b = h >> 7;
        stageE[i] = (tail[e] & 0xFFFF) | ((etyp[e] - 1) << 16) | ((h & 127) << 20);
        stageB[i] = (unsigned short)b;
        atomicAdd(&hist[b], 1);
    }
    __syncthreads();
    // exclusive scan of 512 bins: 2 bins/thread + 256-ladder
    int a0 = hist[2 * tid], a1 = hist[2 * tid + 1];
    int s2 = a0 + a1;
    psum[tid] = s2;
    __syncthreads();
    for (int d = 1; d < 256; d <<= 1) {
        int t = (tid >= d) ? psum[tid - d] : 0;
        __syncthreads();
        psum[tid] += t;
        __syncthreads();
    }
    int excl = psum[tid] - s2;
    boff_s[2 * tid] = excl;
    boff_s[2 * tid + 1] = excl + a0;
    __syncthreads();
    for (int i = tid; i < CHUNK; i += 256) {
        int b = stageB[i];
        int pos = boff_s[b] + atomicAdd(&fctr[b], 1);
        stage2[pos] = stageE[i];
    }
    __syncthreads();
    for (int i = tid; i < CHUNK; i += 256) barr[lo + i] = stage2[i];
    for (int i = tid; i < NB; i += 256)
        pack[blk * NB + i] = (boff_s[i] << 8) | fctr[i];
    // fused cvt (independent streaming work)
    for (int i = blk * 256 + tid; i < N_ENT * (CH / 2); i += PART_BLOCKS * 256) {
        float2 v = *(const float2*)(ent + 2 * (size_t)i);
        emb[i] = f2bf_bits(v.x) | (f2bf_bits(v.y) << 16);
    }
}

// per bucket: gather the 800 part-block windows to LDS, then sort entries by
// key = (rowgroup:5 | g2:2 | row:2) where g2 = tail>>14 (4 supergroups of
// 16K rows = 3.2 MB gather window, L2-resident chip-wide). Every (g2,row)
// run is PADDED to a multiple of 8 with dummy entries (rel=15 -> zero
// weight), so each 8-edge hop chunk maps to exactly one row. Emits:
//   deg_arr[h]       true in-degree (mean divisor)
//   cpk[grg*4+r]     4 packed bytes: chunk count per g2 for row r
//   rg_off[grg]      csr start (multiple of 8 -> 32B-aligned meta loads)
//   csr              padded entries: tail | rel<<16
__global__ __launch_bounds__(1024) void gc_place_kernel(const int* __restrict__ barr,
                                                        const int* __restrict__ pack,
                                                        int* __restrict__ deg_arr,
                                                        int* __restrict__ rg_off,
                                                        int* __restrict__ cpk,
                                                        int* __restrict__ csr) {
    __shared__ int ent_s[BCAP];
    __shared__ int psum[1024];
    __shared__ int kcnt[NKEY];
    __shared__ int kctr[NKEY];
    __shared__ int kbase[NKEY];
    int b = blockIdx.x, tid = threadIdx.x;
    if (tid < NKEY) { kcnt[tid] = 0; kctr[tid] = 0; }
    int c = 0, o = 0;
    if (tid < PART_BLOCKS) {
        int pk = pack[tid * NB + b];
        c = pk & 255;
        o = pk >> 8;
    }
    psum[tid] = c;
    __syncthreads();
    for (int d = 1; d < 1024; d <<= 1) {
        int t = (tid >= d) ? psum[tid - d] : 0;
        __syncthreads();
        psum[tid] += t;
        __syncthreads();
    }
    int my_off = psum[tid] - c;
    int n = psum[1023];
    const int* src = barr + tid * CHUNK + o;
    for (int k = 0; k < c; ++k) ent_s[my_off + k] = src[k];
    __syncthreads();
    // histogram over 512 keys
    for (int i = tid; i < n; i += 1024) {
        int e = ent_s[i];
        int hl = (e >> 20) & 127;
        int key = ((hl >> 2) << 4) | (((e >> 14) & 3) << 2) | (hl & 3);
        atomicAdd(&kcnt[key], 1);
    }
    __syncthreads();
    // per-row degree + packed per-g2 chunk counts (tid<128: rgl=tid>>2, r=tid&3)
    if (tid < 128) {
        int rgl = tid >> 2, r = tid & 3;
        int base = (rgl << 4) | r;
        int c0 = kcnt[base], c1 = kcnt[base + 4], c2 = kcnt[base + 8], c3 = kcnt[base + 12];
        int h = (b << 7) + tid;
        if (h < N_ENT) {
            deg_arr[h] = c0 + c1 + c2 + c3;
            cpk[(((b << 5) + rgl) << 2) + r] =
                ((c0 + 7) >> 3) | (((c1 + 7) >> 3) << 8) |
                (((c2 + 7) >> 3) << 16) | (((c3 + 7) >> 3) << 24);
        }
    }
    // padded exclusive scan over 512 bins (2 bins/thread on first 256 threads)
    int a0 = 0, a1 = 0, s2 = 0;
    if (tid < 256) {
        a0 = (kcnt[2 * tid] + 7) & ~7;
        a1 = (kcnt[2 * tid + 1] + 7) & ~7;
        s2 = a0 + a1;
        psum[tid] = s2;
    }
    __syncthreads();
    for (int d = 1; d < 256; d <<= 1) {
        int t = (tid < 256 && tid >= d) ? psum[tid - d] : 0;
        __syncthreads();
        if (tid < 256) psum[tid] += t;
        __syncthreads();
    }
    if (tid < 256) {
        int excl = psum[tid] - s2;
        kbase[2 * tid] = excl;
        kbase[2 * tid + 1] = excl + a0;
    }
    __syncthreads();
    int lo = b * BCAP_P;
    if (tid < 32) {
        int grg = (b << 5) + tid;
        if (grg < NRG) rg_off[grg] = lo + kbase[tid << 4];
    }
    // scatter real entries (strip hlow bits; keep tail | rel<<16)
    for (int i = tid; i < n; i += 1024) {
        int e = ent_s[i];
        int hl = (e >> 20) & 127;
        int key = ((hl >> 2) << 4) | (((e >> 14) & 3) << 2) | (hl & 3);
        int pos = lo + kbase[key] + atomicAdd(&kctr[key], 1);
        csr[pos] = e & 0xFFFFF;
    }
    __syncthreads();
    // pad fill: dummy = rel 15 (zero weight row), tail 0
    if (tid < NKEY) {
        int cc = kcnt[tid];
        int pc = (cc + 7) & ~7;
        int p0 = lo + kbase[tid];
        for (int k = cc; k < pc; ++k) csr[p0 + k] = 15 << 16;
    }
}

// one wave64 per 4 rows, 12500 waves. r6 diagnosis: per-chunk serial chain
// meta(~300cy) -> RFL -> gathers(~300) -> lds(~150) -> FMA was the floor.
// This round: META SOFTWARE-PIPELINE — the meta int4 pair rolls in VGPRs;
// RFL consumes the buffer issued ONE FULL CHUNK AGO (latency hidden under
// the previous chunk's gathers+FMA), then the next 32B load is issued
// immediately. Stream is contiguous across runs/rowgroups -> handoff is
// free; the final dangling prefetch reads <=32B past the stream (csr is
// followed by deg_arr in the workspace -> in bounds).
__global__ __launch_bounds__(256, 8) void gc_hop_kernel(
        const unsigned int* __restrict__ src,     // bf16x2 per uint
        const int* __restrict__ deg_arr,
        const int* __restrict__ rg_off,
        const int* __restrict__ cpk,
        const int* __restrict__ csr,
        const float* __restrict__ wt,
        unsigned int* __restrict__ dst,
        float* __restrict__ res,
        const float* __restrict__ ent,
        const unsigned int* __restrict__ yprev,
        int mode) {
    __shared__ float wt_s[16 * CH];   // rows 10..15 ZERO (dummy rel=15 -> 0)
    for (int i = threadIdx.x; i < 16 * CH; i += 256)
        wt_s[i] = (i < N_RELM1 * CH) ? wt[i] : 0.f;
    __syncthreads();

    int wave = threadIdx.x >> 6, lane = threadIdx.x & 63;
    int rg = RFL(blockIdx.x * 4 + wave);
    if (rg >= NRG) return;    // no barriers below

    int4 dd = ((const int4*)deg_arr)[rg];
    int4 cc = ((const int4*)cpk)[rg];
    int segv = rg_off[rg];

    int D0 = RFL(dd.x), D1 = RFL(dd.y), D2 = RFL(dd.z), D3 = RFL(dd.w);
    int C0 = RFL(cc.x), C1 = RFL(cc.y), C2 = RFL(cc.z), C3 = RFL(cc.w);
    int seg = RFL(segv);

    const int4* mp = (const int4*)(csr + seg);   // 32B-aligned (seg % 8 == 0)
    int4 mB0 = mp[0], mB1 = mp[1];               // chunk 0 meta in flight
    mp += 2;

    float ax0 = 0.f, ay0 = 0.f, ax1 = 0.f, ay1 = 0.f;
    float ax2 = 0.f, ay2 = 0.f, ax3 = 0.f, ay3 = 0.f;

    const unsigned* srcl = src + lane;                  // lane offset folded once
    const float2*   wl   = (const float2*)wt_s + lane;  // wt_s[rel*CH + 2*lane]

#define CHUNK8(axr, ayr) { \
    int p0_ = RFL(mB0.x), p1_ = RFL(mB0.y), p2_ = RFL(mB0.z), p3_ = RFL(mB0.w); \
    int p4_ = RFL(mB1.x), p5_ = RFL(mB1.y), p6_ = RFL(mB1.z), p7_ = RFL(mB1.w); \
    mB0 = mp[0]; mB1 = mp[1]; mp += 2; \
    unsigned v0_ = srcl[(unsigned)(p0_ & 0xFFFF) * 64u]; \
    unsigned v1_ = srcl[(unsigned)(p1_ & 0xFFFF) * 64u]; \
    unsigned v2_ = srcl[(unsigned)(p2_ & 0xFFFF) * 64u]; \
    unsigned v3_ = srcl[(unsigned)(p3_ & 0xFFFF) * 64u]; \
    unsigned v4_ = srcl[(unsigned)(p4_ & 0xFFFF) * 64u]; \
    unsigned v5_ = srcl[(unsigned)(p5_ & 0xFFFF) * 64u]; \
    unsigned v6_ = srcl[(unsigned)(p6_ & 0xFFFF) * 64u]; \
    unsigned v7_ = srcl[(unsigned)(p7_ & 0xFFFF) * 64u]; \
    float2 w0_ = wl[((p0_ >> 16) & 15) * 64]; \
    float2 w1_ = wl[((p1_ >> 16) & 15) * 64]; \
    float2 w2_ = wl[((p2_ >> 16) & 15) * 64]; \
    float2 w3_ = wl[((p3_ >> 16) & 15) * 64]; \
    float2 w4_ = wl[((p4_ >> 16) & 15) * 64]; \
    float2 w5_ = wl[((p5_ >> 16) & 15) * 64]; \
    float2 w6_ = wl[((p6_ >> 16) & 15) * 64]; \
    float2 w7_ = wl[((p7_ >> 16) & 15) * 64]; \
    axr = fmaf(__uint_as_float(v0_ << 16), w0_.x, axr); \
    ayr = fmaf(__uint_as_float(v0_ & 0xFFFF0000u), w0_.y, ayr); \
    axr = fmaf(__uint_as_float(v1_ << 16), w1_.x, axr); \
    ayr = fmaf(__uint_as_float(v1_ & 0xFFFF0000u), w1_.y, ayr); \
    axr = fmaf(__uint_as_float(v2_ << 16), w2_.x, axr); \
    ayr = fmaf(__uint_as_float(v2_ & 0xFFFF0000u), w2_.y, ayr); \
    axr = fmaf(__uint_as_float(v3_ << 16), w3_.x, axr); \
    ayr = fmaf(__uint_as_float(v3_ & 0xFFFF0000u), w3_.y, ayr); \
    axr = fmaf(__uint_as_float(v4_ << 16), w4_.x, axr); \
    ayr = fmaf(__uint_as_float(v4_ & 0xFFFF0000u), w4_.y, ayr); \
    axr = fmaf(__uint_as_float(v5_ << 16), w5_.x, axr); \
    ayr = fmaf(__uint_as_float(v5_ & 0xFFFF0000u), w5_.y, ayr); \
    axr = fmaf(__uint_as_float(v6_ << 16), w6_.x, axr); \
    ayr = fmaf(__uint_as_float(v6_ & 0xFFFF0000u), w6_.y, ayr); \
    axr = fmaf(__uint_as_float(v7_ << 16), w7_.x, axr); \
    ayr = fmaf(__uint_as_float(v7_ & 0xFFFF0000u), w7_.y, ayr); \
}

#define RUN(axr, ayr, Cr) { \
    int n_ = (Cr >> sh) & 255; \
    for (int c_ = 0; c_ < n_; ++c_) CHUNK8(axr, ayr) \
}

    for (int g2 = 0; g2 < 4; ++g2) {
        int sh = g2 << 3;
        RUN(ax0, ay0, C0)
        RUN(ax1, ay1, C1)
        RUN(ax2, ay2, C2)
        RUN(ax3, ay3, C3)
    }
#undef RUN
#undef CHUNK8

#define ROWOUT(r, axr, ayr, Dr) { \
        int row = (rg << 2) + r; \
        float invd = 1.0f / fmaxf((float)Dr, 1.0f); \
        float x0 = axr * invd, x1 = ayr * invd; \
        float s = x0 * x0 + x1 * x1; \
        _Pragma("unroll") \
        for (int o = 32; o; o >>= 1) s += __shfl_xor(s, o, 64); \
        float inv = 1.0f / fmaxf(sqrtf(s), EPS_N); \
        float y0 = x0 * inv, y1v = x1 * inv; \
        if (mode == 0) { \
            dst[(row << 6) + lane] = f2bf_bits(y0) | (f2bf_bits(y1v) << 16); \
        } else { \
            unsigned p1 = yprev[(row << 6) + lane]; \
            unsigned p2 = src[(row << 6) + lane]; \
            int base = (row << 7) + 2 * lane; \
            float2 e = *(const float2*)(ent + base); \
            float2 o2; \
            o2.x = e.x + __uint_as_float(p1 << 16) \
                       + __uint_as_float(p2 << 16) + y0; \
            o2.y = e.y + __uint_as_float(p1 & 0xFFFF0000u) \
                       + __uint_as_float(p2 & 0xFFFF0000u) + y1v; \
            *(float2*)(res + base) = o2; \
        } }

    ROWOUT(0, ax0, ay0, D0);
    ROWOUT(1, ax1, ay1, D1);
    ROWOUT(2, ax2, ay2, D2);
    ROWOUT(3, ax3, ay3, D3);
#undef ROWOUT
}

extern "C" void kernel_launch(void* const* d_in, const int* in_sizes, int n_in,
                              void* d_out, int out_size, void* d_ws, size_t ws_size,
                              hipStream_t stream) {
    const float* ent  = (const float*)d_in[0];
    const int*   eidx = (const int*)d_in[1];   // [2, E]: head row 0, tail row 1
    const int*   etyp = (const int*)d_in[2];
    const float* wt   = (const float*)d_in[3];
    float*       res  = (float*)d_out;

    const int* head = eidx;
    const int* tail = eidx + N_EDGES;

    // workspace layout (~38.9 MB). barr+pack ALIAS embB (dead until hop1).
    // csr is followed by deg_arr/rg_off/cpk so the hop's one dangling 32B
    // meta prefetch past a stream end stays in-bounds.
    unsigned int* embA = (unsigned int*)d_ws;                 // 12.8 MB
    unsigned int* embB = embA + (size_t)N_ENT * 64;           // 12.8 MB
    int* barr = (int*)embB;                                   // alias (6.4 MB)
    int* pack = (int*)embB + N_EDGES;                         // alias (1.25 MB)
    int* csr     = (int*)(embB + (size_t)N_ENT * 64);         // 12.8 MB (NB*BCAP_P)
    int* deg_arr = csr + (size_t)NB * BCAP_P;                 // 0.2 MB
    int* rg_off  = deg_arr + N_ENT;                           // NRG (pad 12544)
    int* cpk     = rg_off + 12544;                            // 0.2 MB

    gc_part_kernel<<<PART_BLOCKS, 256, 0, stream>>>(head, tail, etyp, barr, pack,
                                                    ent, embA);
    gc_place_kernel<<<NB, 1024, 0, stream>>>(barr, pack, deg_arr, rg_off, cpk, csr);

    const int hop_grid = NRG / 4;   // 3125 blocks of 4 waves = 12500 waves
    // hop1: y1 -> embB
    gc_hop_kernel<<<hop_grid, 256, 0, stream>>>(embA, deg_arr, rg_off, cpk, csr,
                                                wt, embB, res, ent, embB, 0);
    // hop2: y2 -> embA
    gc_hop_kernel<<<hop_grid, 256, 0, stream>>>(embB, deg_arr, rg_off, cpk, csr,
                                                wt, embA, res, ent, embB, 0);
    // hop3: gathers from embA (y2), reads embB (y1) + ent, writes res only
    gc_hop_kernel<<<hop_grid, 256, 0, stream>>>(embA, deg_arr, rg_off, cpk, csr,
                                                wt, embB, res, ent, embB, 1);
}